// Round 4
// baseline (150.357 us; speedup 1.0000x reference)
//
#include <hip/hip_runtime.h>
#include <hip/hip_bf16.h>

typedef unsigned short u16;
typedef __attribute__((ext_vector_type(8))) short short8;
typedef __attribute__((ext_vector_type(4))) float f32x4;

#define HID 128
#define WNUMEL 3072
#define OUTD 144

// ---------- fused pre-pass: W2 swizzle | MLP | sh+rank, dispatched by block range ----------
__global__ void k_pre(const float* __restrict__ W2, __hip_bfloat16* __restrict__ W2s,
                      const float* __restrict__ es, const float* __restrict__ W1,
                      const float* __restrict__ b1, __hip_bfloat16* __restrict__ h2s,
                      const float* __restrict__ ev, const int* __restrict__ dst,
                      float* __restrict__ shb, int* __restrict__ cnti,
                      int* __restrict__ pos, int E, int NW, int NM) {
  __shared__ float esl[8][32];
  const int b = blockIdx.x, tid = threadIdx.x;
  if (b < NW) {
    // W2 reorder: bf16, swizzled so B-fragments are lane-linear
    int t = b * 256 + tid;                            // < 128*3072
    int i = t & 7, lane = (t >> 3) & 63, s = (t >> 9) & 3, tt = t >> 11;
    int c = lane & 15, h = lane >> 4;
    W2s[t] = __float2bfloat16(W2[(32 * s + 8 * h + i) * WNUMEL + 16 * tt + c]);
  } else if (b < NW + NM) {
    // MLP: h2 = silu(es@W1+b1) * 0.125, stored bf16 pre-swizzled
    int e0 = (b - NW) * 8;
    {
      int e = e0 + (tid >> 5);
      esl[tid >> 5][tid & 31] = (e < E) ? es[e * 32 + (tid & 31)] : 0.f;
    }
    __syncthreads();
    int h = tid & 127;
    float bh = b1[h];
#pragma unroll
    for (int r = 0; r < 4; ++r) {
      int eloc = (tid >> 7) + r * 2;
      int e = e0 + eloc;
      if (e < E) {
        float acc = bh;
#pragma unroll
        for (int i = 0; i < 32; ++i) acc = fmaf(esl[eloc][i], W1[i * HID + h], acc);
        float sg = 1.f / (1.f + expf(-acc));
        float z = acc * sg * 0.125f;                  // fold 1/sqrt(64)
        int s = h >> 5, hh = (h >> 3) & 3, i = h & 7;
        int lane = (e & 15) + 16 * hh, eblk = e >> 4;
        h2s[((size_t)(eblk * 4 + s) * 64 + lane) * 8 + i] = __float2bfloat16(z);
      }
    }
  } else {
    // sh + per-dst rank
    int e = (b - NW - NM) * 256 + tid;
    if (e >= E) return;
    float vx = ev[e * 3 + 0], vy = ev[e * 3 + 1], vz = ev[e * 3 + 2];
    float nrm = fmaxf(sqrtf(vx * vx + vy * vy + vz * vz), 1e-9f);
    float x = vx / nrm, y = vy / nrm, z = vz / nrm;
    const float SQ3 = 1.7320508075688772f, SQ5 = 2.2360679774997896f,
                SQ15 = 3.872983346207417f;
    float* sp = shb + (size_t)e * 9;
    sp[0] = 1.f;
    sp[1] = SQ3 * x; sp[2] = SQ3 * y; sp[3] = SQ3 * z;
    sp[4] = SQ15 * x * y; sp[5] = SQ15 * y * z;
    sp[6] = 0.5f * SQ5 * (3.f * z * z - 1.f);
    sp[7] = SQ15 * x * z;
    sp[8] = 0.5f * SQ15 * (x * x - y * y);
    pos[e] = atomicAdd(&cnti[dst[e]], 1);
  }
}

// ---------- single-block exclusive scan: off = exscan(cnti), off[n]=E ----------
__global__ void k_scan(const int* __restrict__ cnti, int* __restrict__ off, int n, int E) {
  __shared__ int ts[1024];
  int tid = threadIdx.x;
  int m = (n + 1023) >> 10;
  int lo = tid * m, hi = min(lo + m, n);
  int s = 0;
  for (int i = lo; i < hi; ++i) s += cnti[i];
  ts[tid] = s;
  __syncthreads();
  for (int d = 1; d < 1024; d <<= 1) {
    int v = (tid >= d) ? ts[tid - d] : 0;
    __syncthreads();
    ts[tid] += v;
    __syncthreads();
  }
  int run = (tid > 0) ? ts[tid - 1] : 0;
  for (int i = lo; i < hi; ++i) { off[i] = run; run += cnti[i]; }
  if (tid == 0) off[n] = E;
}

// ---------- fill CSR edge list ----------
__global__ void k_slot(const int* __restrict__ dst, const int* __restrict__ pos,
                       const int* __restrict__ off, int* __restrict__ elist, int E) {
  int e = blockIdx.x * 256 + threadIdx.x;
  if (e < E) elist[off[dst[e]] + pos[e]] = e;
}

// ---------- fused GEMM + x-contraction + sh expand -> msg ----------
// grid = E/64. 4 waves. All 3 l-paths in one block: A loaded ONCE and pinned in
// VGPRs (anti-remat asm). Wave w owns N-tiles {l3*64 + n*4 + w} (stride-4
// interleave so all waves cross l3 boundaries together; 2 barriers per l3).
__global__ __launch_bounds__(256, 3) void k_gemm(
    const u16* __restrict__ h2s, const u16* __restrict__ W2s,
    const float* __restrict__ hsrc, const int* __restrict__ srci,
    const float* __restrict__ shb, const float* __restrict__ b2,
    float* __restrict__ msg, int E) {
  __shared__ float xT[4096];           // [u(64)][e(64)] 16KB
  __shared__ float fl[4096];           // [wave][eloc(64)][v(16)] 16KB, reused per l3
  __shared__ float shl[640];           // sh staged [64e][10]
  const int tid = threadIdx.x, lane = tid & 63, wave = tid >> 6;
  const int blk = blockIdx.x;
  const int c = lane & 15, g = lane >> 4;

  // stage x transposed (wave w stages u-rows [w*16, w*16+16))
  {
    int e = lane, u0 = wave * 16;
    int eg = min(blk * 64 + e, E - 1);
    const float* xr = hsrc + (size_t)srci[eg] * 64 + u0;
#pragma unroll
    for (int k = 0; k < 16; ++k) xT[(u0 + k) * 64 + e] = xr[k];
  }
  // stage sh
#pragma unroll
  for (int r = 0; r < 3; ++r) {
    int idx = r * 256 + tid;
    if (idx < 576) {
      int ee = idx / 9, jj = idx - ee * 9;
      int eg = blk * 64 + ee;
      shl[ee * 10 + jj] = (eg < E) ? shb[(size_t)eg * 9 + jj] : 0.f;
    }
  }
  // A fragments: 4 M-tiles x 4 k-steps, loaded once, PINNED in VGPRs
  short8 af[4][4];
#pragma unroll
  for (int mt = 0; mt < 4; ++mt)
#pragma unroll
    for (int s = 0; s < 4; ++s) {
      af[mt][s] = *(const short8*)(h2s + ((size_t)((blk * 4 + mt) * 4 + s) * 64 + lane) * 8);
      asm volatile("" : "+v"(af[mt][s]));   // block load-rematerialization
    }
  __syncthreads();

#pragma unroll 1
  for (int l3 = 0; l3 < 3; ++l3) {
    float feat[4][4] = {};
#pragma unroll
    for (int n = 0; n < 16; ++n) {
      const int u = n * 4 + wave;              // this tile's u index
      const int T = l3 * 64 + u;               // global N-tile
      const u16* Bg = W2s + (size_t)T * 2048;  // T*4*64*8
      short8 bf[4];
#pragma unroll
      for (int s = 0; s < 4; ++s)
        bf[s] = *(const short8*)(Bg + (s * 64 + lane) * 8);
      float b2v = 0.125f * b2[T * 16 + c];
#pragma unroll
      for (int mt = 0; mt < 4; ++mt) {
        f32x4 acc = {0.f, 0.f, 0.f, 0.f};
#pragma unroll
        for (int s = 0; s < 4; ++s)
          acc = __builtin_amdgcn_mfma_f32_16x16x32_bf16(af[mt][s], bf[s], acc, 0, 0, 0);
        const float4 xv = *(const float4*)&xT[u * 64 + mt * 16 + g * 4];
#pragma unroll
        for (int j = 0; j < 4; ++j)
          feat[mt][j] = fmaf((&xv.x)[j], acc[j] + b2v, feat[mt][j]);
      }
    }
    // flush this wave's partial feat (its u-subset) to LDS
#pragma unroll
    for (int mt = 0; mt < 4; ++mt)
#pragma unroll
      for (int j = 0; j < 4; ++j)
        fl[wave * 1024 + (mt * 16 + g * 4 + j) * 16 + c] = feat[mt][j];
    __syncthreads();
    // epilogue for this l3: sum 4 waves, expand with sh, stream to msg
    const int nel = (l3 == 0) ? 1024 : (l3 == 1) ? 3072 : 5120;
    for (int p = tid; p < nel; p += 256) {
      int eloc, outoff;
      float mult;
      if (l3 == 0) {
        eloc = p >> 4; outoff = p & 15; mult = 1.f;
      } else if (l3 == 1) {
        eloc = p / 48; int id = p - eloc * 48; int mm = id % 3;
        outoff = 16 + id; mult = shl[eloc * 10 + 1 + mm];
      } else {
        eloc = p / 80; int id = p - eloc * 80; int mm = id % 5;
        outoff = 64 + id; mult = shl[eloc * 10 + 4 + mm];
      }
      int v = (l3 == 0) ? (p & 15) : (l3 == 1) ? ((p - eloc * 48) / 3) : ((p - eloc * 80) / 5);
      int q = eloc * 16 + v;
      float f = fl[q] + fl[1024 + q] + fl[2048 + q] + fl[3072 + q];
      int e = blk * 64 + eloc;
      if (e < E) msg[(size_t)e * OUTD + outoff] = f * mult;
    }
    __syncthreads();                   // protect fl before next l3 rewrites it
  }
}

// ---------- gather: 4 threads per dst (36 floats each), mean over edges ----------
__global__ void k_gather(const float* __restrict__ msg, const int* __restrict__ off,
                         const int* __restrict__ elist, float* __restrict__ out, int n_dst) {
  int d = blockIdx.x * 64 + (threadIdx.x >> 2);
  int q = threadIdx.x & 3;
  if (d >= n_dst) return;
  int a = off[d], b = off[d + 1];
  float4 acc[9] = {};
  for (int i = a; i < b; ++i) {
    const float4* row = (const float4*)(msg + (size_t)elist[i] * OUTD + q * 36);
#pragma unroll
    for (int k = 0; k < 9; ++k) {
      float4 m = row[k];
      acc[k].x += m.x; acc[k].y += m.y; acc[k].z += m.z; acc[k].w += m.w;
    }
  }
  float inv = 1.f / (float)max(b - a, 1);
  float4* orow = (float4*)(out + (size_t)d * OUTD + q * 36);
#pragma unroll
  for (int k = 0; k < 9; ++k) {
    acc[k].x *= inv; acc[k].y *= inv; acc[k].z *= inv; acc[k].w *= inv;
    orow[k] = acc[k];
  }
}

extern "C" void kernel_launch(void* const* d_in, const int* in_sizes, int n_in,
                              void* d_out, int out_size, void* d_ws, size_t ws_size,
                              hipStream_t stream) {
  const float* h_src        = (const float*)d_in[0];
  const float* edge_vec     = (const float*)d_in[1];
  const float* edge_scalars = (const float*)d_in[2];
  const float* W1           = (const float*)d_in[3];
  const float* b1           = (const float*)d_in[4];
  const float* W2           = (const float*)d_in[5];
  const float* b2           = (const float*)d_in[6];
  const int*   src_idx      = (const int*)d_in[7];
  const int*   dst_idx      = (const int*)d_in[8];

  const int E = in_sizes[1] / 3;
  const int n_dst = out_size / OUTD;
  const int nblk64 = (E + 63) / 64;
  const size_t E_pad = (size_t)nblk64 * 64;

  char* w = (char*)d_ws;
  auto al = [](size_t x) { return (x + 255) & ~(size_t)255; };
  size_t o = 0;
  float* shb = (float*)(w + o);                   o += al(E_pad * 9 * 4);
  __hip_bfloat16* h2s = (__hip_bfloat16*)(w + o); o += al(E_pad * 128 * 2);
  __hip_bfloat16* W2s = (__hip_bfloat16*)(w + o); o += al((size_t)128 * 3072 * 2);
  float* msg = (float*)(w + o);                   o += al(E_pad * OUTD * 4);
  int* cnti  = (int*)(w + o);                     o += al((size_t)n_dst * 4);
  int* pos   = (int*)(w + o);                     o += al((size_t)E * 4);
  int* off   = (int*)(w + o);                     o += al((size_t)(n_dst + 1) * 4);
  int* elist = (int*)(w + o);                     o += al((size_t)E * 4);

  hipMemsetAsync(cnti, 0, (size_t)n_dst * 4, stream);

  const int NW = (128 * WNUMEL) / 256;            // 1536 w2s blocks
  const int NM = (E + 7) / 8;                     // mlp blocks
  const int NP = (E + 255) / 256;                 // prep blocks
  k_pre<<<NW + NM + NP, 256, 0, stream>>>(W2, W2s, edge_scalars, W1, b1, h2s,
                                          edge_vec, dst_idx, shb, cnti, pos, E, NW, NM);
  k_scan<<<1, 1024, 0, stream>>>(cnti, off, n_dst, E);
  k_slot<<<(E + 255) / 256, 256, 0, stream>>>(dst_idx, pos, off, elist, E);
  k_gemm<<<nblk64, 256, 0, stream>>>((const u16*)h2s, (const u16*)W2s, h_src, src_idx,
                                     shb, b2, msg, E);
  k_gather<<<(n_dst + 63) / 64, 256, 0, stream>>>(msg, off, elist, (float*)d_out, n_dst);
}

// Round 5
// 137.795 us; speedup vs baseline: 1.0912x; 1.0912x over previous
//
#include <hip/hip_runtime.h>
#include <hip/hip_bf16.h>

typedef unsigned short u16;
typedef __attribute__((ext_vector_type(8))) short short8;
typedef __attribute__((ext_vector_type(4))) float f32x4;

#define HID 128
#define WNUMEL 3072
#define OUTD 144

// ---------- fused pre-pass: W2 swizzle | MLP | sh+rank, dispatched by block range ----------
__global__ void k_pre(const float* __restrict__ W2, __hip_bfloat16* __restrict__ W2s,
                      const float* __restrict__ es, const float* __restrict__ W1,
                      const float* __restrict__ b1, __hip_bfloat16* __restrict__ h2s,
                      const float* __restrict__ ev, const int* __restrict__ dst,
                      float* __restrict__ shb, int* __restrict__ cnti,
                      int* __restrict__ pos, int E, int NW, int NM) {
  __shared__ float esl[8][32];
  const int b = blockIdx.x, tid = threadIdx.x;
  if (b < NW) {
    int t = b * 256 + tid;                            // < 128*3072
    int i = t & 7, lane = (t >> 3) & 63, s = (t >> 9) & 3, tt = t >> 11;
    int c = lane & 15, h = lane >> 4;
    W2s[t] = __float2bfloat16(W2[(32 * s + 8 * h + i) * WNUMEL + 16 * tt + c]);
  } else if (b < NW + NM) {
    int e0 = (b - NW) * 8;
    {
      int e = e0 + (tid >> 5);
      esl[tid >> 5][tid & 31] = (e < E) ? es[e * 32 + (tid & 31)] : 0.f;
    }
    __syncthreads();
    int h = tid & 127;
    float bh = b1[h];
#pragma unroll
    for (int r = 0; r < 4; ++r) {
      int eloc = (tid >> 7) + r * 2;
      int e = e0 + eloc;
      if (e < E) {
        float acc = bh;
#pragma unroll
        for (int i = 0; i < 32; ++i) acc = fmaf(esl[eloc][i], W1[i * HID + h], acc);
        float sg = 1.f / (1.f + expf(-acc));
        float z = acc * sg * 0.125f;                  // fold 1/sqrt(64)
        int s = h >> 5, hh = (h >> 3) & 3, i = h & 7;
        int lane = (e & 15) + 16 * hh, eblk = e >> 4;
        h2s[((size_t)(eblk * 4 + s) * 64 + lane) * 8 + i] = __float2bfloat16(z);
      }
    }
  } else {
    int e = (b - NW - NM) * 256 + tid;
    if (e >= E) return;
    float vx = ev[e * 3 + 0], vy = ev[e * 3 + 1], vz = ev[e * 3 + 2];
    float nrm = fmaxf(sqrtf(vx * vx + vy * vy + vz * vz), 1e-9f);
    float x = vx / nrm, y = vy / nrm, z = vz / nrm;
    const float SQ3 = 1.7320508075688772f, SQ5 = 2.2360679774997896f,
                SQ15 = 3.872983346207417f;
    float* sp = shb + (size_t)e * 9;
    sp[0] = 1.f;
    sp[1] = SQ3 * x; sp[2] = SQ3 * y; sp[3] = SQ3 * z;
    sp[4] = SQ15 * x * y; sp[5] = SQ15 * y * z;
    sp[6] = 0.5f * SQ5 * (3.f * z * z - 1.f);
    sp[7] = SQ15 * x * z;
    sp[8] = 0.5f * SQ15 * (x * x - y * y);
    pos[e] = atomicAdd(&cnti[dst[e]], 1);
  }
}

// ---------- single-block exclusive scan: off = exscan(cnti), off[n]=E ----------
__global__ void k_scan(const int* __restrict__ cnti, int* __restrict__ off, int n, int E) {
  __shared__ int ts[1024];
  int tid = threadIdx.x;
  int m = (n + 1023) >> 10;
  int lo = tid * m, hi = min(lo + m, n);
  int s = 0;
  for (int i = lo; i < hi; ++i) s += cnti[i];
  ts[tid] = s;
  __syncthreads();
  for (int d = 1; d < 1024; d <<= 1) {
    int v = (tid >= d) ? ts[tid - d] : 0;
    __syncthreads();
    ts[tid] += v;
    __syncthreads();
  }
  int run = (tid > 0) ? ts[tid - 1] : 0;
  for (int i = lo; i < hi; ++i) { off[i] = run; run += cnti[i]; }
  if (tid == 0) off[n] = E;
}

// ---------- fill CSR edge list ----------
__global__ void k_slot(const int* __restrict__ dst, const int* __restrict__ pos,
                       const int* __restrict__ off, int* __restrict__ elist, int E) {
  int e = blockIdx.x * 256 + threadIdx.x;
  if (e < E) elist[off[dst[e]] + pos[e]] = e;
}

// ---------- fused GEMM + x-contraction + sh expand -> msg ----------
// grid = (E/64, 3). 4 waves; wave owns 16 contiguous N-tiles of l-path blockIdx.y.
// A pinned in VGPRs (no remat); B register-double-buffered (hide L2 latency);
// b2 folded into MFMA acc init. B straight from L2 (W2s = 786 KB resident).
__global__ __launch_bounds__(256, 3) void k_gemm(
    const u16* __restrict__ h2s, const u16* __restrict__ W2s,
    const float* __restrict__ hsrc, const int* __restrict__ srci,
    const float* __restrict__ shb, const float* __restrict__ b2,
    float* __restrict__ msg, int E) {
  __shared__ float lds[4160];          // xT[64u][64e] (16KB), then fl[4][1040]
  __shared__ float shl[640];           // sh staged [64e][10]
  float* xT = lds;
  float* fl = lds;
  const int tid = threadIdx.x, lane = tid & 63, wave = tid >> 6;
  const int blk = blockIdx.x, l3 = blockIdx.y;
  const int c = lane & 15, g = lane >> 4;

  // A fragments first (long-latency, issue early), then PIN in VGPRs
  short8 af[4][4];
#pragma unroll
  for (int mt = 0; mt < 4; ++mt)
#pragma unroll
    for (int s = 0; s < 4; ++s) {
      af[mt][s] = *(const short8*)(h2s + ((size_t)((blk * 4 + mt) * 4 + s) * 64 + lane) * 8);
      asm volatile("" : "+v"(af[mt][s]));   // block load-rematerialization
    }

  // stage x transposed (wave w stages u-rows [w*16, w*16+16))
  {
    int e = lane, u0 = wave * 16;
    int eg = min(blk * 64 + e, E - 1);
    const float* xr = hsrc + (size_t)srci[eg] * 64 + u0;
#pragma unroll
    for (int k = 0; k < 16; ++k) xT[(u0 + k) * 64 + e] = xr[k];
  }
  // stage sh for epilogue (l>=1 only)
  if (l3 > 0) {
#pragma unroll
    for (int r = 0; r < 3; ++r) {
      int idx = r * 256 + tid;
      if (idx < 576) {
        int ee = idx / 9, jj = idx - ee * 9;
        int eg = blk * 64 + ee;
        shl[ee * 10 + jj] = (eg < E) ? shb[(size_t)eg * 9 + jj] : 0.f;
      }
    }
  }

  const int T0 = l3 * 64 + wave * 16;
  const u16* Bg = W2s + (size_t)T0 * 2048;
  const float* b2g = b2 + T0 * 16 + c;
  float feat[4][4] = {};
  short8 bfA[4], bfB[4];

  auto LOADB = [&](short8* BF, int K) {
    const u16* bp = Bg + (size_t)K * 2048 + lane * 8;
#pragma unroll
    for (int s = 0; s < 4; ++s) BF[s] = *(const short8*)(bp + s * 512);
  };
  auto COMPUTE = [&](const short8* BF, int K) {
    float b2v = 0.125f * b2g[K * 16];
    const float* xb = &xT[(wave * 16 + K) * 64 + g * 4];
#pragma unroll
    for (int mt = 0; mt < 4; ++mt) {
      f32x4 acc = {b2v, b2v, b2v, b2v};
#pragma unroll
      for (int s = 0; s < 4; ++s)
        acc = __builtin_amdgcn_mfma_f32_16x16x32_bf16(af[mt][s], BF[s], acc, 0, 0, 0);
      const float4 xv = *(const float4*)(xb + mt * 16);
#pragma unroll
      for (int j = 0; j < 4; ++j)
        feat[mt][j] = fmaf((&xv.x)[j], acc[j], feat[mt][j]);
    }
  };

  LOADB(bfA, 0);                       // prologue prefetch (before barrier: global only)
  __syncthreads();

#pragma unroll
  for (int kk = 0; kk < 8; ++kk) {     // 16 tiles, 2-stage register pipeline
    LOADB(bfB, 2 * kk + 1);
    COMPUTE(bfA, 2 * kk);
    if (kk < 7) LOADB(bfA, 2 * kk + 2);
    COMPUTE(bfB, 2 * kk + 1);
  }

  // cross-wave feat reduction in LDS (reuses xT space — barrier first)
  __syncthreads();
#pragma unroll
  for (int mt = 0; mt < 4; ++mt)
#pragma unroll
    for (int j = 0; j < 4; ++j)
      fl[wave * 1040 + (mt * 16 + g * 4 + j) * 16 + c] = feat[mt][j];
  __syncthreads();

  // epilogue: msg = feat (x) sh, coalesced streaming stores
  const int nel = (l3 == 0) ? 1024 : (l3 == 1) ? 3072 : 5120;
  for (int p = tid; p < nel; p += 256) {
    int eloc, outoff;
    float mult;
    if (l3 == 0) {
      eloc = p >> 4; outoff = p & 15; mult = 1.f;
    } else if (l3 == 1) {
      eloc = p / 48; int id = p - eloc * 48; int mm = id % 3;
      outoff = 16 + id; mult = shl[eloc * 10 + 1 + mm];
    } else {
      eloc = p / 80; int id = p - eloc * 80; int mm = id % 5;
      outoff = 64 + id; mult = shl[eloc * 10 + 4 + mm];
    }
    int v = (l3 == 0) ? (p & 15) : (l3 == 1) ? ((p - eloc * 48) / 3) : ((p - eloc * 80) / 5);
    int q = eloc * 16 + v;
    float f = fl[q] + fl[1040 + q] + fl[2080 + q] + fl[3120 + q];
    int e = blk * 64 + eloc;
    if (e < E) msg[(size_t)e * OUTD + outoff] = f * mult;
  }
}

// ---------- gather: 4 threads per dst (36 floats each), mean over edges ----------
__global__ void k_gather(const float* __restrict__ msg, const int* __restrict__ off,
                         const int* __restrict__ elist, float* __restrict__ out, int n_dst) {
  int d = blockIdx.x * 64 + (threadIdx.x >> 2);
  int q = threadIdx.x & 3;
  if (d >= n_dst) return;
  int a = off[d], b = off[d + 1];
  float4 acc[9] = {};
  for (int i = a; i < b; ++i) {
    const float4* row = (const float4*)(msg + (size_t)elist[i] * OUTD + q * 36);
#pragma unroll
    for (int k = 0; k < 9; ++k) {
      float4 m = row[k];
      acc[k].x += m.x; acc[k].y += m.y; acc[k].z += m.z; acc[k].w += m.w;
    }
  }
  float inv = 1.f / (float)max(b - a, 1);
  float4* orow = (float4*)(out + (size_t)d * OUTD + q * 36);
#pragma unroll
  for (int k = 0; k < 9; ++k) {
    acc[k].x *= inv; acc[k].y *= inv; acc[k].z *= inv; acc[k].w *= inv;
    orow[k] = acc[k];
  }
}

extern "C" void kernel_launch(void* const* d_in, const int* in_sizes, int n_in,
                              void* d_out, int out_size, void* d_ws, size_t ws_size,
                              hipStream_t stream) {
  const float* h_src        = (const float*)d_in[0];
  const float* edge_vec     = (const float*)d_in[1];
  const float* edge_scalars = (const float*)d_in[2];
  const float* W1           = (const float*)d_in[3];
  const float* b1           = (const float*)d_in[4];
  const float* W2           = (const float*)d_in[5];
  const float* b2           = (const float*)d_in[6];
  const int*   src_idx      = (const int*)d_in[7];
  const int*   dst_idx      = (const int*)d_in[8];

  const int E = in_sizes[1] / 3;
  const int n_dst = out_size / OUTD;
  const int nblk64 = (E + 63) / 64;
  const size_t E_pad = (size_t)nblk64 * 64;

  char* w = (char*)d_ws;
  auto al = [](size_t x) { return (x + 255) & ~(size_t)255; };
  size_t o = 0;
  float* shb = (float*)(w + o);                   o += al(E_pad * 9 * 4);
  __hip_bfloat16* h2s = (__hip_bfloat16*)(w + o); o += al(E_pad * 128 * 2);
  __hip_bfloat16* W2s = (__hip_bfloat16*)(w + o); o += al((size_t)128 * 3072 * 2);
  float* msg = (float*)(w + o);                   o += al(E_pad * OUTD * 4);
  int* cnti  = (int*)(w + o);                     o += al((size_t)n_dst * 4);
  int* pos   = (int*)(w + o);                     o += al((size_t)E * 4);
  int* off   = (int*)(w + o);                     o += al((size_t)(n_dst + 1) * 4);
  int* elist = (int*)(w + o);                     o += al((size_t)E * 4);

  hipMemsetAsync(cnti, 0, (size_t)n_dst * 4, stream);

  const int NW = (128 * WNUMEL) / 256;            // 1536 w2s blocks
  const int NM = (E + 7) / 8;                     // mlp blocks
  const int NP = (E + 255) / 256;                 // prep blocks
  k_pre<<<NW + NM + NP, 256, 0, stream>>>(W2, W2s, edge_scalars, W1, b1, h2s,
                                          edge_vec, dst_idx, shb, cnti, pos, E, NW, NM);
  k_scan<<<1, 1024, 0, stream>>>(cnti, off, n_dst, E);
  k_slot<<<(E + 255) / 256, 256, 0, stream>>>(dst_idx, pos, off, elist, E);
  dim3 gg(nblk64, 3);
  k_gemm<<<gg, 256, 0, stream>>>((const u16*)h2s, (const u16*)W2s, h_src, src_idx,
                                 shb, b2, msg, E);
  k_gather<<<(n_dst + 63) / 64, 256, 0, stream>>>(msg, off, elist, (float*)d_out, n_dst);
}

// Round 6
// 108.279 us; speedup vs baseline: 1.3886x; 1.2726x over previous
//
#include <hip/hip_runtime.h>
#include <hip/hip_bf16.h>

typedef unsigned short u16;
typedef __attribute__((ext_vector_type(8))) short short8;
typedef __attribute__((ext_vector_type(4))) float f32x4;

#define HID 128
#define WNUMEL 3072
#define OUTD 144

// ---------- fused pre-pass: W2 swizzle | MLP | sh+rank, dispatched by block range ----------
__global__ void k_pre(const float* __restrict__ W2, __hip_bfloat16* __restrict__ W2s,
                      const float* __restrict__ es, const float* __restrict__ W1,
                      const float* __restrict__ b1, __hip_bfloat16* __restrict__ h2s,
                      const float* __restrict__ ev, const int* __restrict__ dst,
                      float* __restrict__ shb, int* __restrict__ cnti,
                      int* __restrict__ pos, int E, int NW, int NM) {
  __shared__ float esl[8][32];
  const int b = blockIdx.x, tid = threadIdx.x;
  if (b < NW) {
    int t = b * 256 + tid;                            // < 128*3072
    int i = t & 7, lane = (t >> 3) & 63, s = (t >> 9) & 3, tt = t >> 11;
    int c = lane & 15, h = lane >> 4;
    W2s[t] = __float2bfloat16(W2[(32 * s + 8 * h + i) * WNUMEL + 16 * tt + c]);
  } else if (b < NW + NM) {
    int e0 = (b - NW) * 8;
    {
      int e = e0 + (tid >> 5);
      esl[tid >> 5][tid & 31] = (e < E) ? es[e * 32 + (tid & 31)] : 0.f;
    }
    __syncthreads();
    int h = tid & 127;
    float bh = b1[h];
#pragma unroll
    for (int r = 0; r < 4; ++r) {
      int eloc = (tid >> 7) + r * 2;
      int e = e0 + eloc;
      if (e < E) {
        float acc = bh;
#pragma unroll
        for (int i = 0; i < 32; ++i) acc = fmaf(esl[eloc][i], W1[i * HID + h], acc);
        float sg = 1.f / (1.f + expf(-acc));
        float z = acc * sg * 0.125f;                  // fold 1/sqrt(64)
        int s = h >> 5, hh = (h >> 3) & 3, i = h & 7;
        int lane = (e & 15) + 16 * hh, eblk = e >> 4;
        h2s[((size_t)(eblk * 4 + s) * 64 + lane) * 8 + i] = __float2bfloat16(z);
      }
    }
  } else {
    int e = (b - NW - NM) * 256 + tid;
    if (e >= E) return;
    float vx = ev[e * 3 + 0], vy = ev[e * 3 + 1], vz = ev[e * 3 + 2];
    float nrm = fmaxf(sqrtf(vx * vx + vy * vy + vz * vz), 1e-9f);
    float x = vx / nrm, y = vy / nrm, z = vz / nrm;
    const float SQ3 = 1.7320508075688772f, SQ5 = 2.2360679774997896f,
                SQ15 = 3.872983346207417f;
    float* sp = shb + (size_t)e * 9;
    sp[0] = 1.f;
    sp[1] = SQ3 * x; sp[2] = SQ3 * y; sp[3] = SQ3 * z;
    sp[4] = SQ15 * x * y; sp[5] = SQ15 * y * z;
    sp[6] = 0.5f * SQ5 * (3.f * z * z - 1.f);
    sp[7] = SQ15 * x * z;
    sp[8] = 0.5f * SQ15 * (x * x - y * y);
    pos[e] = atomicAdd(&cnti[dst[e]], 1);
  }
}

// ---------- single-block exclusive scan: off = exscan(cnti), off[n]=E ----------
__global__ void k_scan(const int* __restrict__ cnti, int* __restrict__ off, int n, int E) {
  __shared__ int ts[1024];
  int tid = threadIdx.x;
  int m = (n + 1023) >> 10;
  int lo = tid * m, hi = min(lo + m, n);
  int s = 0;
  for (int i = lo; i < hi; ++i) s += cnti[i];
  ts[tid] = s;
  __syncthreads();
  for (int d = 1; d < 1024; d <<= 1) {
    int v = (tid >= d) ? ts[tid - d] : 0;
    __syncthreads();
    ts[tid] += v;
    __syncthreads();
  }
  int run = (tid > 0) ? ts[tid - 1] : 0;
  for (int i = lo; i < hi; ++i) { off[i] = run; run += cnti[i]; }
  if (tid == 0) off[n] = E;
}

// ---------- fill CSR edge list ----------
__global__ void k_slot(const int* __restrict__ dst, const int* __restrict__ pos,
                       const int* __restrict__ off, int* __restrict__ elist, int E) {
  int e = blockIdx.x * 256 + threadIdx.x;
  if (e < E) elist[off[dst[e]] + pos[e]] = e;
}

// ---------- fused GEMM + x-contraction -> feat[E][48] ----------
// grid = (E/64, 3). 4 waves; wave owns 16 contiguous N-tiles of l-path blockIdx.y.
// R3 inner loop (compiler-scheduled, no pins) + launch_bounds(256,4) for 16 waves/CU.
// Stores compact feat (48 floats/edge) — sh expansion deferred to k_gather.
__global__ __launch_bounds__(256, 4) void k_gemm(
    const u16* __restrict__ h2s, const u16* __restrict__ W2s,
    const float* __restrict__ hsrc, const int* __restrict__ srci,
    const float* __restrict__ b2, float* __restrict__ feat_out, int E) {
  __shared__ float lds[4160];          // xT[64u][64e] (16KB), then fl[4][1040]
  float* xT = lds;
  float* fl = lds;
  const int tid = threadIdx.x, lane = tid & 63, wave = tid >> 6;
  const int blk = blockIdx.x, l3 = blockIdx.y;
  const int c = lane & 15, g = lane >> 4;

  // stage x transposed (wave w stages u-rows [w*16, w*16+16) — its own use)
  {
    int e = lane, u0 = wave * 16;
    int eg = min(blk * 64 + e, E - 1);
    const float* xr = hsrc + (size_t)srci[eg] * 64 + u0;
#pragma unroll
    for (int k = 0; k < 16; ++k) xT[(u0 + k) * 64 + e] = xr[k];
  }
  // A fragments: 4 M-tiles x 4 k-steps (compiler may remat from L1 — that's fine)
  short8 af[4][4];
#pragma unroll
  for (int mt = 0; mt < 4; ++mt)
#pragma unroll
    for (int s = 0; s < 4; ++s)
      af[mt][s] = *(const short8*)(h2s + ((size_t)((blk * 4 + mt) * 4 + s) * 64 + lane) * 8);
  __syncthreads();

  float feat[4][4] = {};               // [mt][j], this l-path, this wave's u-range
  const int T0 = l3 * 64 + wave * 16;
  const u16* Bg = W2s + (size_t)T0 * 2048;
  const float* b2g = b2 + T0 * 16 + c;

#pragma unroll
  for (int k = 0; k < 16; ++k) {       // wave's 16 N-tiles, no barriers
    short8 bf[4];
#pragma unroll
    for (int s = 0; s < 4; ++s)
      bf[s] = *(const short8*)(Bg + ((size_t)(k * 4 + s) * 64 + lane) * 8);
    float b2v = 0.125f * b2g[k * 16];
#pragma unroll
    for (int mt = 0; mt < 4; ++mt) {
      f32x4 acc = {b2v, b2v, b2v, b2v};
#pragma unroll
      for (int s = 0; s < 4; ++s)
        acc = __builtin_amdgcn_mfma_f32_16x16x32_bf16(af[mt][s], bf[s], acc, 0, 0, 0);
      const float4 xv = *(const float4*)&xT[(wave * 16 + k) * 64 + mt * 16 + g * 4];
#pragma unroll
      for (int j = 0; j < 4; ++j)
        feat[mt][j] = fmaf((&xv.x)[j], acc[j], feat[mt][j]);
    }
  }

  // cross-wave feat reduction in LDS (reuses xT space — barrier first)
  __syncthreads();
#pragma unroll
  for (int mt = 0; mt < 4; ++mt)
#pragma unroll
    for (int j = 0; j < 4; ++j)
      fl[wave * 1040 + (mt * 16 + g * 4 + j) * 16 + c] = feat[mt][j];
  __syncthreads();

  // epilogue: sum the 4 wave-partials, store compact feat slice for this l3
#pragma unroll
  for (int r = 0; r < 4; ++r) {
    int p = r * 256 + tid;             // 1024 = 64 edges x 16 v
    int eloc = p >> 4, v = p & 15;
    float f = fl[p] + fl[1040 + p] + fl[2080 + p] + fl[3120 + p];
    int e = blk * 64 + eloc;
    if (e < E) feat_out[(size_t)e * 48 + l3 * 16 + v] = f;
  }
}

// ---------- gather: one wave per dst; apply sh during accumulation; mean ----------
__global__ void k_gather(const float* __restrict__ feat, const float* __restrict__ shb,
                         const int* __restrict__ off, const int* __restrict__ elist,
                         float* __restrict__ out, int n_dst) {
  int d = blockIdx.x * 4 + (threadIdx.x >> 6);
  int lane = threadIdx.x & 63;
  if (d >= n_dst || lane >= 36) return;
  // lane handles output floats [4*lane, 4*lane+4): precompute (feat idx, sh idx)
  int fi[4], si[4];
#pragma unroll
  for (int r = 0; r < 4; ++r) {
    int o = lane * 4 + r;
    if (o < 16)      { fi[r] = o;                 si[r] = 0; }        // sh[0] == 1
    else if (o < 64) { int id = o - 16; fi[r] = 16 + id / 3; si[r] = 1 + id % 3; }
    else             { int id = o - 64; fi[r] = 32 + id / 5; si[r] = 4 + id % 5; }
  }
  int a = off[d], b = off[d + 1];
  float4 acc = {0.f, 0.f, 0.f, 0.f};
  for (int i = a; i < b; ++i) {
    int e = elist[i];
    const float* fp = feat + (size_t)e * 48;
    const float* sp = shb + (size_t)e * 9;
#pragma unroll
    for (int r = 0; r < 4; ++r)
      (&acc.x)[r] = fmaf(fp[fi[r]], sp[si[r]], (&acc.x)[r]);
  }
  float inv = 1.f / (float)max(b - a, 1);
  acc.x *= inv; acc.y *= inv; acc.z *= inv; acc.w *= inv;
  *(float4*)&out[(size_t)d * OUTD + lane * 4] = acc;
}

extern "C" void kernel_launch(void* const* d_in, const int* in_sizes, int n_in,
                              void* d_out, int out_size, void* d_ws, size_t ws_size,
                              hipStream_t stream) {
  const float* h_src        = (const float*)d_in[0];
  const float* edge_vec     = (const float*)d_in[1];
  const float* edge_scalars = (const float*)d_in[2];
  const float* W1           = (const float*)d_in[3];
  const float* b1           = (const float*)d_in[4];
  const float* W2           = (const float*)d_in[5];
  const float* b2           = (const float*)d_in[6];
  const int*   src_idx      = (const int*)d_in[7];
  const int*   dst_idx      = (const int*)d_in[8];

  const int E = in_sizes[1] / 3;
  const int n_dst = out_size / OUTD;
  const int nblk64 = (E + 63) / 64;
  const size_t E_pad = (size_t)nblk64 * 64;

  char* w = (char*)d_ws;
  auto al = [](size_t x) { return (x + 255) & ~(size_t)255; };
  size_t o = 0;
  float* shb = (float*)(w + o);                   o += al(E_pad * 9 * 4);
  __hip_bfloat16* h2s = (__hip_bfloat16*)(w + o); o += al(E_pad * 128 * 2);
  __hip_bfloat16* W2s = (__hip_bfloat16*)(w + o); o += al((size_t)128 * 3072 * 2);
  float* featb = (float*)(w + o);                 o += al(E_pad * 48 * 4);
  int* cnti  = (int*)(w + o);                     o += al((size_t)n_dst * 4);
  int* pos   = (int*)(w + o);                     o += al((size_t)E * 4);
  int* off   = (int*)(w + o);                     o += al((size_t)(n_dst + 1) * 4);
  int* elist = (int*)(w + o);                     o += al((size_t)E * 4);

  hipMemsetAsync(cnti, 0, (size_t)n_dst * 4, stream);

  const int NW = (128 * WNUMEL) / 256;            // 1536 w2s blocks
  const int NM = (E + 7) / 8;                     // mlp blocks
  const int NP = (E + 255) / 256;                 // prep blocks
  k_pre<<<NW + NM + NP, 256, 0, stream>>>(W2, W2s, edge_scalars, W1, b1, h2s,
                                          edge_vec, dst_idx, shb, cnti, pos, E, NW, NM);
  k_scan<<<1, 1024, 0, stream>>>(cnti, off, n_dst, E);
  k_slot<<<(E + 255) / 256, 256, 0, stream>>>(dst_idx, pos, off, elist, E);
  dim3 gg(nblk64, 3);
  k_gemm<<<gg, 256, 0, stream>>>((const u16*)h2s, (const u16*)W2s, h_src, src_idx,
                                 b2, featb, E);
  k_gather<<<(n_dst + 3) / 4, 256, 0, stream>>>(featb, shb, off, elist,
                                                (float*)d_out, n_dst);
}

// Round 7
// 95.226 us; speedup vs baseline: 1.5789x; 1.1371x over previous
//
#include <hip/hip_runtime.h>
#include <hip/hip_bf16.h>

typedef unsigned short u16;
typedef __attribute__((ext_vector_type(8))) short short8;
typedef __attribute__((ext_vector_type(4))) float f32x4;

#define HID 128
#define WNUMEL 3072
#define OUTD 144

// ---------- fused pre-pass: W2 swizzle | MLP | sh + linked-list build ----------
__global__ void k_pre(const float* __restrict__ W2, __hip_bfloat16* __restrict__ W2s,
                      const float* __restrict__ es, const float* __restrict__ W1,
                      const float* __restrict__ b1, __hip_bfloat16* __restrict__ h2s,
                      const float* __restrict__ ev, const int* __restrict__ dst,
                      float* __restrict__ shb, int* __restrict__ head,
                      int* __restrict__ nxt, int E, int NW, int NM) {
  __shared__ float esl[8][32];
  const int b = blockIdx.x, tid = threadIdx.x;
  if (b < NW) {
    int t = b * 256 + tid;                            // < 128*3072
    int i = t & 7, lane = (t >> 3) & 63, s = (t >> 9) & 3, tt = t >> 11;
    int c = lane & 15, h = lane >> 4;
    W2s[t] = __float2bfloat16(W2[(32 * s + 8 * h + i) * WNUMEL + 16 * tt + c]);
  } else if (b < NW + NM) {
    int e0 = (b - NW) * 8;
    {
      int e = e0 + (tid >> 5);
      esl[tid >> 5][tid & 31] = (e < E) ? es[e * 32 + (tid & 31)] : 0.f;
    }
    __syncthreads();
    int h = tid & 127;
    float bh = b1[h];
#pragma unroll
    for (int r = 0; r < 4; ++r) {
      int eloc = (tid >> 7) + r * 2;
      int e = e0 + eloc;
      if (e < E) {
        float acc = bh;
#pragma unroll
        for (int i = 0; i < 32; ++i) acc = fmaf(esl[eloc][i], W1[i * HID + h], acc);
        float sg = 1.f / (1.f + expf(-acc));
        float z = acc * sg * 0.125f;                  // fold 1/sqrt(64)
        int s = h >> 5, hh = (h >> 3) & 3, i = h & 7;
        int lane = (e & 15) + 16 * hh, eblk = e >> 4;
        h2s[((size_t)(eblk * 4 + s) * 64 + lane) * 8 + i] = __float2bfloat16(z);
      }
    }
  } else {
    int e = (b - NW - NM) * 256 + tid;
    if (e >= E) return;
    float vx = ev[e * 3 + 0], vy = ev[e * 3 + 1], vz = ev[e * 3 + 2];
    float nrm = fmaxf(sqrtf(vx * vx + vy * vy + vz * vz), 1e-9f);
    float x = vx / nrm, y = vy / nrm, z = vz / nrm;
    const float SQ3 = 1.7320508075688772f, SQ5 = 2.2360679774997896f,
                SQ15 = 3.872983346207417f;
    float* sp = shb + (size_t)e * 9;
    sp[0] = 1.f;
    sp[1] = SQ3 * x; sp[2] = SQ3 * y; sp[3] = SQ3 * z;
    sp[4] = SQ15 * x * y; sp[5] = SQ15 * y * z;
    sp[6] = 0.5f * SQ5 * (3.f * z * z - 1.f);
    sp[7] = SQ15 * x * z;
    sp[8] = 0.5f * SQ15 * (x * x - y * y);
    nxt[e] = atomicExch(&head[dst[e]], e);           // per-dst linked list
  }
}

// ---------- fused GEMM + x-contraction -> feat[E][48] ----------
// grid = (E/64, 3). 4 waves; wave owns 16 contiguous N-tiles of l-path blockIdx.y.
// R6 loop + A-fragments PINNED in VGPRs (asm "+v" after staging: loads overlap
// the xT writes; the pin makes later MFMA uses consume the asm result, which
// the compiler cannot re-materialize as an L1 reload).
__global__ __launch_bounds__(256, 4) void k_gemm(
    const u16* __restrict__ h2s, const u16* __restrict__ W2s,
    const float* __restrict__ hsrc, const int* __restrict__ srci,
    const float* __restrict__ b2, float* __restrict__ feat_out, int E) {
  __shared__ float lds[4160];          // xT[64u][64e] (16KB), then fl[4][1040]
  float* xT = lds;
  float* fl = lds;
  const int tid = threadIdx.x, lane = tid & 63, wave = tid >> 6;
  const int blk = blockIdx.x, l3 = blockIdx.y;
  const int c = lane & 15, g = lane >> 4;

  // A fragments: issue loads first (long latency)
  short8 af[4][4];
#pragma unroll
  for (int mt = 0; mt < 4; ++mt)
#pragma unroll
    for (int s = 0; s < 4; ++s)
      af[mt][s] = *(const short8*)(h2s + ((size_t)((blk * 4 + mt) * 4 + s) * 64 + lane) * 8);

  // stage x transposed (wave w stages u-rows [w*16, w*16+16))
  {
    int e = lane, u0 = wave * 16;
    int eg = min(blk * 64 + e, E - 1);
    const float* xr = hsrc + (size_t)srci[eg] * 64 + u0;
#pragma unroll
    for (int k = 0; k < 16; ++k) xT[(u0 + k) * 64 + e] = xr[k];
  }

  // pin A in VGPRs (waits land here, after the staging stores were issued)
#pragma unroll
  for (int mt = 0; mt < 4; ++mt)
#pragma unroll
    for (int s = 0; s < 4; ++s)
      asm volatile("" : "+v"(af[mt][s]));
  __syncthreads();

  float feat[4][4] = {};               // [mt][j], this l-path, this wave's u-range
  const int T0 = l3 * 64 + wave * 16;
  const u16* Bg = W2s + (size_t)T0 * 2048;
  const float* b2g = b2 + T0 * 16 + c;

#pragma unroll
  for (int k = 0; k < 16; ++k) {       // wave's 16 N-tiles, no barriers
    short8 bf[4];
#pragma unroll
    for (int s = 0; s < 4; ++s)
      bf[s] = *(const short8*)(Bg + ((size_t)(k * 4 + s) * 64 + lane) * 8);
    float b2v = 0.125f * b2g[k * 16];
#pragma unroll
    for (int mt = 0; mt < 4; ++mt) {
      f32x4 acc = {b2v, b2v, b2v, b2v};
#pragma unroll
      for (int s = 0; s < 4; ++s)
        acc = __builtin_amdgcn_mfma_f32_16x16x32_bf16(af[mt][s], bf[s], acc, 0, 0, 0);
      const float4 xv = *(const float4*)&xT[(wave * 16 + k) * 64 + mt * 16 + g * 4];
#pragma unroll
      for (int j = 0; j < 4; ++j)
        feat[mt][j] = fmaf((&xv.x)[j], acc[j], feat[mt][j]);
    }
  }

  // cross-wave feat reduction in LDS (reuses xT space — barrier first)
  __syncthreads();
#pragma unroll
  for (int mt = 0; mt < 4; ++mt)
#pragma unroll
    for (int j = 0; j < 4; ++j)
      fl[wave * 1040 + (mt * 16 + g * 4 + j) * 16 + c] = feat[mt][j];
  __syncthreads();

  // epilogue: sum the 4 wave-partials, store compact feat slice for this l3
#pragma unroll
  for (int r = 0; r < 4; ++r) {
    int p = r * 256 + tid;             // 1024 = 64 edges x 16 v
    int eloc = p >> 4, v = p & 15;
    float f = fl[p] + fl[1040 + p] + fl[2080 + p] + fl[3120 + p];
    int e = blk * 64 + eloc;
    if (e < E) feat_out[(size_t)e * 48 + l3 * 16 + v] = f;
  }
}

// ---------- gather: one wave per dst; walk linked list; apply sh; mean ----------
__global__ void k_gather(const float* __restrict__ feat, const float* __restrict__ shb,
                         const int* __restrict__ head, const int* __restrict__ nxt,
                         float* __restrict__ out, int n_dst) {
  int d = blockIdx.x * 4 + (threadIdx.x >> 6);
  int lane = threadIdx.x & 63;
  if (d >= n_dst) return;
  // lane handles output floats [4*lane, 4*lane+4): precompute (feat idx, sh idx)
  int fi[4], si[4];
#pragma unroll
  for (int r = 0; r < 4; ++r) {
    int o = lane * 4 + r;
    if (o < 16)      { fi[r] = o;                 si[r] = 0; }        // sh[0] == 1
    else if (o < 64) { int id = o - 16; fi[r] = 16 + id / 3; si[r] = 1 + id % 3; }
    else             { int id = o - 64; fi[r] = 32 + id / 5; si[r] = 4 + id % 5; }
  }
  int e = head[d];                     // same addr across lanes -> broadcast load
  float4 acc = {0.f, 0.f, 0.f, 0.f};
  int deg = 0;
  while (e >= 0) {
    int en = nxt[e];                   // issue next-pointer first (chase overlap)
    if (lane < 36) {
      const float* fp = feat + (size_t)e * 48;
      const float* sp = shb + (size_t)e * 9;
#pragma unroll
      for (int r = 0; r < 4; ++r)
        (&acc.x)[r] = fmaf(fp[fi[r]], sp[si[r]], (&acc.x)[r]);
    }
    ++deg;
    e = en;
  }
  if (lane < 36) {
    float inv = 1.f / (float)max(deg, 1);
    acc.x *= inv; acc.y *= inv; acc.z *= inv; acc.w *= inv;
    *(float4*)&out[(size_t)d * OUTD + lane * 4] = acc;
  }
}

extern "C" void kernel_launch(void* const* d_in, const int* in_sizes, int n_in,
                              void* d_out, int out_size, void* d_ws, size_t ws_size,
                              hipStream_t stream) {
  const float* h_src        = (const float*)d_in[0];
  const float* edge_vec     = (const float*)d_in[1];
  const float* edge_scalars = (const float*)d_in[2];
  const float* W1           = (const float*)d_in[3];
  const float* b1           = (const float*)d_in[4];
  const float* W2           = (const float*)d_in[5];
  const float* b2           = (const float*)d_in[6];
  const int*   src_idx      = (const int*)d_in[7];
  const int*   dst_idx      = (const int*)d_in[8];

  const int E = in_sizes[1] / 3;
  const int n_dst = out_size / OUTD;
  const int nblk64 = (E + 63) / 64;
  const size_t E_pad = (size_t)nblk64 * 64;

  char* w = (char*)d_ws;
  auto al = [](size_t x) { return (x + 255) & ~(size_t)255; };
  size_t o = 0;
  float* shb = (float*)(w + o);                   o += al(E_pad * 9 * 4);
  __hip_bfloat16* h2s = (__hip_bfloat16*)(w + o); o += al(E_pad * 128 * 2);
  __hip_bfloat16* W2s = (__hip_bfloat16*)(w + o); o += al((size_t)128 * 3072 * 2);
  float* featb = (float*)(w + o);                 o += al(E_pad * 48 * 4);
  int* head  = (int*)(w + o);                     o += al((size_t)n_dst * 4);
  int* nxt   = (int*)(w + o);                     o += al((size_t)E * 4);

  hipMemsetAsync(head, 0xFF, (size_t)n_dst * 4, stream);   // head = -1

  const int NW = (128 * WNUMEL) / 256;            // 1536 w2s blocks
  const int NM = (E + 7) / 8;                     // mlp blocks
  const int NP = (E + 255) / 256;                 // prep blocks
  k_pre<<<NW + NM + NP, 256, 0, stream>>>(W2, W2s, edge_scalars, W1, b1, h2s,
                                          edge_vec, dst_idx, shb, head, nxt, E, NW, NM);
  dim3 gg(nblk64, 3);
  k_gemm<<<gg, 256, 0, stream>>>((const u16*)h2s, (const u16*)W2s, h_src, src_idx,
                                 b2, featb, E);
  k_gather<<<(n_dst + 3) / 4, 256, 0, stream>>>(featb, shb, head, nxt,
                                                (float*)d_out, n_dst);
}